// Round 11
// baseline (152.690 us; speedup 1.0000x reference)
//
#include <hip/hip_runtime.h>
#include <hip/hip_bf16.h>
#include <hip/hip_fp8.h>

// Problem constants
#define N_USER 55485
#define N_ITEM 5986
#define NN     61471        // total nodes
#define NE     1500000      // edges

#define NCOARSE 241         // coarse buckets of 256 nodes
#define CCAP    7168        // per-coarse capacity (mean 6224, sigma ~79 -> +12 sigma)
#define CH1     2048        // scatter1 chunk (edges per block)
#define S1_BLOCKS ((NE + CH1 - 1) / CH1)   // 733

#define NFINE   (NCOARSE * 8)   // 1928 fine buckets of 32 nodes
#define BCAPF   1280            // per-fine capacity (mean 781, sigma ~28)
#define SPW     (BCAPF / 2)     // sortedF u32 words per bucket (640)

typedef __attribute__((ext_vector_type(8))) short short8;
typedef __attribute__((ext_vector_type(8))) unsigned short ushort8x;
typedef __attribute__((ext_vector_type(4))) float f32x4;
typedef __attribute__((ext_vector_type(2))) float f32x2;

__device__ __forceinline__ unsigned short f2bf(float f) {
    unsigned u = __float_as_uint(f);
    return (unsigned short)((u + 0x7fffu + ((u >> 16) & 1u)) >> 16);
}
__device__ __forceinline__ float bfu(unsigned short u) {
    return __uint_as_float((unsigned)u << 16);
}
__device__ __forceinline__ unsigned char f2fp8(float f) {
#if __has_builtin(__builtin_amdgcn_cvt_pk_fp8_f32)
    return (unsigned char)(__builtin_amdgcn_cvt_pk_fp8_f32(f, f, 0, false) & 0xff);
#else
    return (unsigned char)__hip_cvt_float_to_fp8(f, __HIP_SATFINITE, __HIP_E4M3);
#endif
}
// decode 4 packed fp8 (one u32) -> 4 f32
__device__ __forceinline__ void fp8x4(unsigned u, float* o) {
#if __has_builtin(__builtin_amdgcn_cvt_pk_f32_fp8)
    f32x2 lo = __builtin_amdgcn_cvt_pk_f32_fp8(u, false);
    f32x2 hi = __builtin_amdgcn_cvt_pk_f32_fp8(u, true);
    o[0] = lo[0]; o[1] = lo[1]; o[2] = hi[0]; o[3] = hi[1];
#else
    #pragma unroll
    for (int i = 0; i < 4; ++i) {
        __half_raw hr = __hip_cvt_fp8_to_halfraw((unsigned char)(u >> (8 * i)), __HIP_E4M3);
        o[i] = __half2float(__half(hr));
    }
#endif
}

// ---------------------------------------------------------------------------
// Fused kernel A: blocks [0, S1_BLOCKS) run scatter pass 1 (LDS multisplit
// into 241 coarse buckets); blocks [S1_BLOCKS, S1_BLOCKS+961) run GEMM1:
//   bufA[NN][128] fp8  = X @ W1l   (mean part, gathered by agg1)
//   bufR[NN][128] bf16 = X @ W1r   (root part, streamed once)
// ---------------------------------------------------------------------------
__global__ __launch_bounds__(256) void fused1_kernel(
    const int* __restrict__ src, const int* __restrict__ dst,
    int* __restrict__ gcur, unsigned* __restrict__ pairsC,
    const float* __restrict__ user, const float* __restrict__ item,
    const float* __restrict__ Wa, const float* __restrict__ Wb,
    unsigned char* __restrict__ bufA, unsigned short* __restrict__ bufR)
{
    __shared__ __align__(16) char smem[65536];
    const int tid = threadIdx.x;

    if (blockIdx.x < S1_BLOCKS) {
        // ================= scatter1 =================
        unsigned* cbuf  = (unsigned*)smem;                    // CH1 * 4 = 8192
        int* cnt_s  = (int*)(smem + CH1 * 4);
        int* off_s  = cnt_s + NCOARSE;
        int* cur_s  = off_s + NCOARSE;
        int* gpos_s = cur_s + NCOARSE;
        const int base = blockIdx.x * CH1;
        const int n    = min(CH1, NE - base);

        for (int i = tid; i < NCOARSE; i += 256) cnt_s[i] = 0;
        __syncthreads();

        unsigned ent[CH1 / 256];
        #pragma unroll
        for (int j = 0; j < CH1 / 256; ++j) {
            int li = j * 256 + tid;
            if (li < n) {
                int e = base + li;
                unsigned d = (unsigned)dst[e];
                unsigned s = (unsigned)src[e];
                unsigned b = d >> 8;
                ent[j] = (b << 24) | ((d & 255u) << 16) | s;
                atomicAdd(&cnt_s[b], 1);
            }
        }
        __syncthreads();

        if (tid < 64) {
            int i0 = tid * 4;
            int c0 = (i0 + 0 < NCOARSE) ? cnt_s[i0 + 0] : 0;
            int c1 = (i0 + 1 < NCOARSE) ? cnt_s[i0 + 1] : 0;
            int c2 = (i0 + 2 < NCOARSE) ? cnt_s[i0 + 2] : 0;
            int c3 = (i0 + 3 < NCOARSE) ? cnt_s[i0 + 3] : 0;
            int s = c0 + c1 + c2 + c3;
            int x = s;
            #pragma unroll
            for (int o = 1; o < 64; o <<= 1) {
                int y = __shfl_up(x, o, 64);
                if (tid >= o) x += y;
            }
            int ex = x - s;
            if (i0 + 0 < NCOARSE) { off_s[i0 + 0] = ex;                cur_s[i0 + 0] = ex; }
            if (i0 + 1 < NCOARSE) { off_s[i0 + 1] = ex + c0;           cur_s[i0 + 1] = ex + c0; }
            if (i0 + 2 < NCOARSE) { off_s[i0 + 2] = ex + c0 + c1;      cur_s[i0 + 2] = ex + c0 + c1; }
            if (i0 + 3 < NCOARSE) { off_s[i0 + 3] = ex + c0 + c1 + c2; cur_s[i0 + 3] = ex + c0 + c1 + c2; }
        }
        __syncthreads();

        #pragma unroll
        for (int j = 0; j < CH1 / 256; ++j) {
            int li = j * 256 + tid;
            if (li < n) {
                unsigned b = ent[j] >> 24;
                int p = atomicAdd(&cur_s[b], 1);
                cbuf[p] = ent[j];
            }
        }
        __syncthreads();

        if (tid < NCOARSE) {
            int len = cnt_s[tid];
            gpos_s[tid] = (len > 0) ? atomicAdd(&gcur[tid], len) : 0;
        }
        __syncthreads();

        for (int i = tid; i < n; i += 256) {
            unsigned e2 = cbuf[i];
            unsigned b  = e2 >> 24;
            int gp = gpos_s[b] + (i - off_s[b]);
            if (gp < CCAP)
                pairsC[(size_t)b * CCAP + gp] = e2 & 0xFFFFFFu;
        }
    } else {
        // ================= GEMM1 (NCOLS=256, fp32 inputs) =================
        short* Wt = (short*)smem;     // 256*128*2 = 65536
        const int gb = blockIdx.x - S1_BLOCKS;
        {
            const int c = tid;
            const float* wcol = (c < 128) ? (Wa + c) : (Wb + (c - 128));
            for (int kc = 0; kc < 16; ++kc) {
                int k = kc * 8;
                short8 tmp;
                #pragma unroll
                for (int j = 0; j < 8; ++j)
                    tmp[j] = (short)f2bf(wcol[(size_t)(k + j) * 128]);
                int chunk = (kc ^ (c & 7));
                *(short8*)&Wt[c * 128 + chunk * 8] = tmp;
            }
        }
        __syncthreads();

        const int wav = tid >> 6, lane = tid & 63;
        const int rowBase = gb * 64 + wav * 16;
        const int r = lane & 15, g = lane >> 4;
        const int row = rowBase + r;
        const int rowC = (row < NN) ? row : (NN - 1);

        f32x4 acc[16];
        #pragma unroll
        for (int t = 0; t < 16; ++t) acc[t] = (f32x4){0.f, 0.f, 0.f, 0.f};

        #pragma unroll
        for (int ks = 0; ks < 4; ++ks) {
            short8 afrag;
            const float* xrow = (rowC < N_USER)
                ? (user + (size_t)rowC * 128)
                : (item + (size_t)(rowC - N_USER) * 128);
            float4 v0 = *(const float4*)(xrow + ks * 32 + g * 8);
            float4 v1 = *(const float4*)(xrow + ks * 32 + g * 8 + 4);
            afrag[0] = (short)f2bf(v0.x); afrag[1] = (short)f2bf(v0.y);
            afrag[2] = (short)f2bf(v0.z); afrag[3] = (short)f2bf(v0.w);
            afrag[4] = (short)f2bf(v1.x); afrag[5] = (short)f2bf(v1.y);
            afrag[6] = (short)f2bf(v1.z); afrag[7] = (short)f2bf(v1.w);
            const int kc = ks * 4 + g;
            #pragma unroll
            for (int t = 0; t < 16; ++t) {
                int c = t * 16 + r;
                short8 bfrag = *(const short8*)&Wt[c * 128 + (kc ^ (c & 7)) * 8];
                acc[t] = __builtin_amdgcn_mfma_f32_16x16x32_bf16(afrag, bfrag, acc[t], 0, 0, 0);
            }
        }

        // cols 0..127 (X@W1l, mean part) -> fp8 bufA; cols 128..255 -> bf16 bufR
        #pragma unroll
        for (int t = 0; t < 16; ++t) {
            #pragma unroll
            for (int q = 0; q < 4; ++q) {
                int orow = rowBase + g * 4 + q;
                if (orow < NN) {
                    if (t < 8)
                        bufA[(size_t)orow * 128 + t * 16 + r] = f2fp8(acc[t][q]);
                    else
                        bufR[(size_t)orow * 128 + (t - 8) * 16 + r] = f2bf(acc[t][q]);
                }
            }
        }
    }
}

// ---------------------------------------------------------------------------
// sort2: one block per FINE bucket. Reads its coarse bucket's stream
// (8 sibling blocks share it; blockIdx remap puts siblings on one XCD so the
// stream is read from L2), filters its 1/8, counting-sorts in LDS, writes
// sortedF + offF directly. Replaces scatter2 AND agg1's sort phase.
// ---------------------------------------------------------------------------
__global__ __launch_bounds__(256) void sort2_kernel(
    const int* __restrict__ gcur, const unsigned* __restrict__ pairsC,
    unsigned* __restrict__ sortedF, int* __restrict__ offF)
{
    // bijective remap: idx = (b%8) + 8*f + 64*(b/8)  -> siblings share XCD
    const int idx = blockIdx.x;
    const int bl = idx & 7;
    const int f  = (idx >> 3) & 7;
    const int bh = idx >> 6;
    const int b  = bh * 8 + bl;
    if (b >= NCOARSE) return;
    const int fb = b * 8 + f;

    __shared__ unsigned cbuf[BCAPF];
    __shared__ __align__(4) unsigned short sp[BCAPF];
    __shared__ int cnt_d[32];
    __shared__ int off_d[33];
    __shared__ int cur_d[32];
    __shared__ int nf;
    const int tid = threadIdx.x;
    if (tid < 32) cnt_d[tid] = 0;
    if (tid == 0) nf = 0;
    __syncthreads();

    const int total = min(gcur[b], CCAP);
    const unsigned* pc = pairsC + (size_t)b * CCAP;
    for (int i = tid; i < total; i += 256) {
        unsigned pk = pc[i];
        if (((pk >> 21) & 7u) == (unsigned)f) {
            int q = atomicAdd(&nf, 1);
            if (q < BCAPF) {
                cbuf[q] = pk;
                atomicAdd(&cnt_d[(pk >> 16) & 31], 1);
            }
        }
    }
    __syncthreads();
    if (tid == 0) {
        int a = 0;
        #pragma unroll
        for (int k = 0; k < 32; ++k) { off_d[k] = a; cur_d[k] = a; a += cnt_d[k]; }
        off_d[32] = a;
    }
    __syncthreads();
    const int cnt = min(nf, BCAPF);
    for (int i = tid; i < cnt; i += 256) {
        unsigned pk = cbuf[i];
        int p = atomicAdd(&cur_d[(pk >> 16) & 31], 1);
        sp[p] = (unsigned short)(pk & 0xffffu);
    }
    __syncthreads();
    for (int i = tid; i * 2 < cnt; i += 256)
        sortedF[(size_t)fb * SPW + i] = ((const unsigned*)sp)[i];
    if (tid < 33) offF[fb * 33 + tid] = off_d[tid];
}

// ---------------------------------------------------------------------------
// GEMM2: out[NN,128](bf16) = x1b[NN,128](bf16) @ [W2l | W2r]
// ---------------------------------------------------------------------------
__global__ __launch_bounds__(256) void mfma_gemm2_kernel(
    const unsigned short* __restrict__ x1b,
    const float* __restrict__ Wa, const float* __restrict__ Wb,
    unsigned short* __restrict__ out)
{
    __shared__ short Wt[128 * 128];
    const int tid = threadIdx.x;
    {
        const int c  = tid & 127;
        const int k0 = (tid >> 7) * 64;
        const float* wcol = (c < 64) ? (Wa + c) : (Wb + (c - 64));
        for (int kc = 0; kc < 8; ++kc) {
            int k = k0 + kc * 8;
            short8 tmp;
            #pragma unroll
            for (int j = 0; j < 8; ++j)
                tmp[j] = (short)f2bf(wcol[(size_t)(k + j) * 64]);
            int chunk = ((k >> 3) ^ (c & 7));
            *(short8*)&Wt[c * 128 + chunk * 8] = tmp;
        }
    }
    __syncthreads();

    const int wav = tid >> 6, lane = tid & 63;
    const int rowBase = blockIdx.x * 64 + wav * 16;
    const int r = lane & 15, g = lane >> 4;
    const int row = rowBase + r;
    const int rowC = (row < NN) ? row : (NN - 1);

    f32x4 acc[8];
    #pragma unroll
    for (int t = 0; t < 8; ++t) acc[t] = (f32x4){0.f, 0.f, 0.f, 0.f};

    #pragma unroll
    for (int ks = 0; ks < 4; ++ks) {
        const unsigned short* xrow = x1b + (size_t)rowC * 128;
        short8 afrag = *(const short8*)(xrow + ks * 32 + g * 8);
        const int kc = ks * 4 + g;
        #pragma unroll
        for (int t = 0; t < 8; ++t) {
            int c = t * 16 + r;
            short8 bfrag = *(const short8*)&Wt[c * 128 + (kc ^ (c & 7)) * 8];
            acc[t] = __builtin_amdgcn_mfma_f32_16x16x32_bf16(afrag, bfrag, acc[t], 0, 0, 0);
        }
    }

    #pragma unroll
    for (int t = 0; t < 8; ++t) {
        #pragma unroll
        for (int q = 0; q < 4; ++q) {
            int orow = rowBase + g * 4 + q;
            if (orow < NN)
                out[(size_t)orow * 128 + t * 16 + r] = f2bf(acc[t][q]);
        }
    }
}

// ---------------------------------------------------------------------------
// Aggregation layer 1 (PURE GATHER — sort hoisted into sort2):
// stage sorted list from global, fp8 wide gather (8 lanes/edge x 16 B,
// 8 edges/wave-inst, unroll x2), fp32 accumulate.
//   x1b[g] = bf16( leaky( mean_j(bufA[j]) + b1 + bufR[g] ) )
// ---------------------------------------------------------------------------
__global__ __launch_bounds__(256) void agg1_kernel(
    const unsigned char* __restrict__ bufA, const unsigned short* __restrict__ bufR,
    const unsigned* __restrict__ sortedF, const int* __restrict__ offF,
    const float* __restrict__ b1, unsigned* __restrict__ x1b)
{
    __shared__ __align__(4) unsigned short sp[BCAPF];
    __shared__ int off_d[33];
    const int b = blockIdx.x, tid = threadIdx.x;
    if (tid < 33) off_d[tid] = offF[b * 33 + tid];
    __syncthreads();
    const int cnt = off_d[32];
    const unsigned* spg = sortedF + (size_t)b * SPW;
    for (int i = tid; i * 2 < cnt; i += 256)
        ((unsigned*)sp)[i] = spg[i];
    __syncthreads();

    const int wid  = tid >> 6, lane = tid & 63;
    const int egrp = lane >> 3;        // 0..7 edge slot
    const int cchk = lane & 7;         // col chunk (16 fp8 = 16 B)

    for (int r = wid; r < 32; r += 4) {
        int g = b * 32 + r;
        if (g >= NN) continue;
        int beg = off_d[r], end = off_d[r + 1];
        float acc[16] = {};
        int p = beg + egrp;
        for (; p + 8 < end; p += 16) {
            int s0 = sp[p], s1 = sp[p + 8];
            uint4 v0 = *(const uint4*)(bufA + (unsigned)s0 * 128 + cchk * 16);
            uint4 v1 = *(const uint4*)(bufA + (unsigned)s1 * 128 + cchk * 16);
            float f0[4], f1[4], f2[4], f3[4];
            fp8x4(v0.x, f0); fp8x4(v0.y, f1); fp8x4(v0.z, f2); fp8x4(v0.w, f3);
            #pragma unroll
            for (int j = 0; j < 4; ++j) {
                acc[j]      += f0[j]; acc[4 + j]  += f1[j];
                acc[8 + j]  += f2[j]; acc[12 + j] += f3[j];
            }
            fp8x4(v1.x, f0); fp8x4(v1.y, f1); fp8x4(v1.z, f2); fp8x4(v1.w, f3);
            #pragma unroll
            for (int j = 0; j < 4; ++j) {
                acc[j]      += f0[j]; acc[4 + j]  += f1[j];
                acc[8 + j]  += f2[j]; acc[12 + j] += f3[j];
            }
        }
        if (p < end) {
            int s0 = sp[p];
            uint4 v0 = *(const uint4*)(bufA + (unsigned)s0 * 128 + cchk * 16);
            float f0[4], f1[4], f2[4], f3[4];
            fp8x4(v0.x, f0); fp8x4(v0.y, f1); fp8x4(v0.z, f2); fp8x4(v0.w, f3);
            #pragma unroll
            for (int j = 0; j < 4; ++j) {
                acc[j]      += f0[j]; acc[4 + j]  += f1[j];
                acc[8 + j]  += f2[j]; acc[12 + j] += f3[j];
            }
        }
        // combine the 8 edge groups
        #pragma unroll
        for (int j = 0; j < 16; ++j) {
            acc[j] += __shfl_xor(acc[j], 32);
            acc[j] += __shfl_xor(acc[j], 16);
            acc[j] += __shfl_xor(acc[j], 8);
        }
        if (egrp == 0) {
            float inv = 1.0f / fmaxf((float)(end - beg), 1.0f);
            const unsigned short* rr = bufR + (size_t)g * 128 + cchk * 16;
            ushort8x rv0 = *(const ushort8x*)rr;
            ushort8x rv1 = *(const ushort8x*)(rr + 8);
            const float* bp = b1 + cchk * 16;
            unsigned w[8];
            #pragma unroll
            for (int jj = 0; jj < 8; ++jj) {
                int j0 = 2 * jj, j1 = 2 * jj + 1;
                float r0 = (jj < 4) ? bfu(rv0[j0 & 7]) : bfu(rv1[j0 & 7]);
                float r1 = (jj < 4) ? bfu(rv0[j1 & 7]) : bfu(rv1[j1 & 7]);
                float o0 = acc[j0] * inv + bp[j0] + r0;
                float o1 = acc[j1] * inv + bp[j1] + r1;
                o0 = (o0 > 0.f) ? o0 : 0.01f * o0;
                o1 = (o1 > 0.f) ? o1 : 0.01f * o1;
                w[jj] = (unsigned)f2bf(o0) | ((unsigned)f2bf(o1) << 16);
            }
            unsigned* xo = x1b + (size_t)g * 64 + cchk * 8;
            *(uint4*)xo       = make_uint4(w[0], w[1], w[2], w[3]);
            *(uint4*)(xo + 4) = make_uint4(w[4], w[5], w[6], w[7]);
        }
    }
}

// ---------------------------------------------------------------------------
// Aggregation layer 2: reuses sort2's sorted lists. 8 lanes/edge x 16 B,
// 8 edges per wave-instruction, unroll x2 (bf16 staging).
//   out[g] = mean_j(buf2[j,0:64]) + b2 + buf2[g,64:128]
// ---------------------------------------------------------------------------
__global__ __launch_bounds__(256) void agg2_kernel(
    const unsigned short* __restrict__ buf2, const unsigned* __restrict__ sortedF,
    const int* __restrict__ offF, const float* __restrict__ b2,
    float* __restrict__ out)
{
    __shared__ __align__(4) unsigned short sp[BCAPF];
    __shared__ int off_d[33];
    const int b = blockIdx.x, tid = threadIdx.x;
    if (tid < 33) off_d[tid] = offF[b * 33 + tid];
    __syncthreads();
    const int cnt = off_d[32];
    const unsigned* spg = sortedF + (size_t)b * SPW;
    for (int i = tid; i * 2 < cnt; i += 256)
        ((unsigned*)sp)[i] = spg[i];
    __syncthreads();

    const int wid  = tid >> 6, lane = tid & 63;
    const int egrp = lane >> 3;        // 0..7 edge slot
    const int cchk = lane & 7;         // col chunk (8 cols = 16 B)

    for (int r = wid; r < 32; r += 4) {
        int g = b * 32 + r;
        if (g >= NN) continue;
        int beg = off_d[r], end = off_d[r + 1];
        float acc[8] = {0.f, 0.f, 0.f, 0.f, 0.f, 0.f, 0.f, 0.f};
        int p = beg + egrp;
        for (; p + 8 < end; p += 16) {
            int s0 = sp[p], s1 = sp[p + 8];
            ushort8x v0 = *(const ushort8x*)(buf2 + (unsigned)s0 * 128 + cchk * 8);
            ushort8x v1 = *(const ushort8x*)(buf2 + (unsigned)s1 * 128 + cchk * 8);
            #pragma unroll
            for (int j = 0; j < 8; ++j) acc[j] += bfu(v0[j]) + bfu(v1[j]);
        }
        if (p < end) {
            int s0 = sp[p];
            ushort8x v0 = *(const ushort8x*)(buf2 + (unsigned)s0 * 128 + cchk * 8);
            #pragma unroll
            for (int j = 0; j < 8; ++j) acc[j] += bfu(v0[j]);
        }
        #pragma unroll
        for (int j = 0; j < 8; ++j) {
            acc[j] += __shfl_xor(acc[j], 32);
            acc[j] += __shfl_xor(acc[j], 16);
            acc[j] += __shfl_xor(acc[j], 8);
        }
        if (egrp == 0) {
            float inv = 1.0f / fmaxf((float)(end - beg), 1.0f);
            ushort8x rv = *(const ushort8x*)(buf2 + (size_t)g * 128 + 64 + cchk * 8);
            float4 bb0 = *(const float4*)(b2 + cchk * 8);
            float4 bb1 = *(const float4*)(b2 + cchk * 8 + 4);
            float bbf[8] = {bb0.x, bb0.y, bb0.z, bb0.w, bb1.x, bb1.y, bb1.z, bb1.w};
            float4 o0, o1;
            o0.x = acc[0] * inv + bbf[0] + bfu(rv[0]);
            o0.y = acc[1] * inv + bbf[1] + bfu(rv[1]);
            o0.z = acc[2] * inv + bbf[2] + bfu(rv[2]);
            o0.w = acc[3] * inv + bbf[3] + bfu(rv[3]);
            o1.x = acc[4] * inv + bbf[4] + bfu(rv[4]);
            o1.y = acc[5] * inv + bbf[5] + bfu(rv[5]);
            o1.z = acc[6] * inv + bbf[6] + bfu(rv[6]);
            o1.w = acc[7] * inv + bbf[7] + bfu(rv[7]);
            *(float4*)&out[(size_t)g * 64 + cchk * 8]     = o0;
            *(float4*)&out[(size_t)g * 64 + cchk * 8 + 4] = o1;
        }
    }
}

// ---------------------------------------------------------------------------
extern "C" void kernel_launch(void* const* d_in, const int* in_sizes, int n_in,
                              void* d_out, int out_size, void* d_ws, size_t ws_size,
                              hipStream_t stream) {
    const float* user = (const float*)d_in[0];
    const float* item = (const float*)d_in[1];
    const float* W1l  = (const float*)d_in[2];
    const float* b1   = (const float*)d_in[3];
    const float* W1r  = (const float*)d_in[4];
    const float* W2l  = (const float*)d_in[5];
    const float* b2   = (const float*)d_in[6];
    const float* W2r  = (const float*)d_in[7];
    const int*   edge = (const int*)d_in[8];
    const int* srcIdx = edge;          // edge_index[0]
    const int* dstIdx = edge + NE;     // edge_index[1]
    float* out = (float*)d_out;

    char* ws = (char*)d_ws;
    size_t off = 0;
    auto alloc = [&](size_t bytes) {
        void* p = ws + off;
        off += (bytes + 255) & ~(size_t)255;
        return p;
    };
    int*      gcur    = (int*)alloc((size_t)NCOARSE * 4);
    unsigned* pairsC  = (unsigned*)alloc((size_t)NCOARSE * CCAP * 4);     // 6.9 MB
    unsigned* sortedF = (unsigned*)alloc((size_t)NFINE * SPW * 4);        // 4.9 MB
    int*      offF    = (int*)alloc((size_t)NFINE * 33 * 4);              // 254 KB
    unsigned char*  bufA = (unsigned char*) alloc((size_t)NN * 128);      // fp8 mean part, 7.9 MB
    unsigned short* bufR = (unsigned short*)alloc((size_t)NN * 128 * 2);  // bf16 root part, 15.7 MB
    unsigned* x1b    = (unsigned*)alloc((size_t)NN * 128 * 2);            // layer-1 act bf16
    unsigned short* buf2 = bufR;   // alias: bufR dead after agg1; GEMM2 out bf16 [N,128]

    (void)hipMemsetAsync(gcur, 0, (size_t)NCOARSE * 4, stream);

    // scatter1 + GEMM1 fused (independent)
    fused1_kernel<<<S1_BLOCKS + 961, 256, 0, stream>>>(
        srcIdx, dstIdx, gcur, pairsC, user, item, W1l, W1r, bufA, bufR);

    // per-fine-bucket sort (replaces scatter2 + agg1's sort phase)
    sort2_kernel<<<1984, 256, 0, stream>>>(gcur, pairsC, sortedF, offF);

    agg1_kernel<<<NFINE, 256, 0, stream>>>(bufA, bufR, sortedF, offF, b1, x1b);

    mfma_gemm2_kernel<<<961, 256, 0, stream>>>((const unsigned short*)x1b, W2l, W2r, buf2);

    agg2_kernel<<<NFINE, 256, 0, stream>>>(buf2, sortedF, offF, b2, out);
}

// Round 12
// 149.590 us; speedup vs baseline: 1.0207x; 1.0207x over previous
//
#include <hip/hip_runtime.h>
#include <hip/hip_bf16.h>
#include <hip/hip_fp8.h>

// Problem constants
#define N_USER 55485
#define N_ITEM 5986
#define NN     61471        // total nodes
#define NE     1500000      // edges

#define NCOARSE 241         // coarse buckets of 256 nodes
#define CCAP    7168        // per-coarse capacity (mean 6224, sigma ~79 -> +12 sigma)
#define CH1     2048        // scatter1 chunk (edges per block)
#define S1_BLOCKS ((NE + CH1 - 1) / CH1)   // 733

#define NFINE   (NCOARSE * 8)   // 1928 fine buckets of 32 nodes
#define BCAPF   1280            // per-fine capacity (mean 781, sigma ~28)
#define CH2     2048
#define S2_SPLIT 4              // CCAP <= S2_SPLIT * CH2
#define SPW     (BCAPF / 2)     // sortedF u32 words per bucket (640)

typedef __attribute__((ext_vector_type(8))) short short8;
typedef __attribute__((ext_vector_type(8))) unsigned short ushort8x;
typedef __attribute__((ext_vector_type(4))) float f32x4;
typedef __attribute__((ext_vector_type(2))) float f32x2;

__device__ __forceinline__ unsigned short f2bf(float f) {
    unsigned u = __float_as_uint(f);
    return (unsigned short)((u + 0x7fffu + ((u >> 16) & 1u)) >> 16);
}
__device__ __forceinline__ float bfu(unsigned short u) {
    return __uint_as_float((unsigned)u << 16);
}
__device__ __forceinline__ unsigned char f2fp8(float f) {
#if __has_builtin(__builtin_amdgcn_cvt_pk_fp8_f32)
    return (unsigned char)(__builtin_amdgcn_cvt_pk_fp8_f32(f, f, 0, false) & 0xff);
#else
    return (unsigned char)__hip_cvt_float_to_fp8(f, __HIP_SATFINITE, __HIP_E4M3);
#endif
}
// decode 4 packed fp8 (one u32) -> 4 f32
__device__ __forceinline__ void fp8x4(unsigned u, float* o) {
#if __has_builtin(__builtin_amdgcn_cvt_pk_f32_fp8)
    f32x2 lo = __builtin_amdgcn_cvt_pk_f32_fp8(u, false);
    f32x2 hi = __builtin_amdgcn_cvt_pk_f32_fp8(u, true);
    o[0] = lo[0]; o[1] = lo[1]; o[2] = hi[0]; o[3] = hi[1];
#else
    #pragma unroll
    for (int i = 0; i < 4; ++i) {
        __half_raw hr = __hip_cvt_fp8_to_halfraw((unsigned char)(u >> (8 * i)), __HIP_E4M3);
        o[i] = __half2float(__half(hr));
    }
#endif
}

// ---------------------------------------------------------------------------
// Fused kernel A: blocks [0, S1_BLOCKS) run scatter pass 1 (LDS multisplit
// into 241 coarse buckets); blocks [S1_BLOCKS, S1_BLOCKS+961) run GEMM1:
//   bufA[NN][128] fp8  = X @ W1l   (mean part, gathered by agg1)
//   bufR[NN][128] bf16 = X @ W1r   (root part, streamed once)
// ---------------------------------------------------------------------------
__global__ __launch_bounds__(256) void fused1_kernel(
    const int* __restrict__ src, const int* __restrict__ dst,
    int* __restrict__ gcur, unsigned* __restrict__ pairsC,
    const float* __restrict__ user, const float* __restrict__ item,
    const float* __restrict__ Wa, const float* __restrict__ Wb,
    unsigned char* __restrict__ bufA, unsigned short* __restrict__ bufR)
{
    __shared__ __align__(16) char smem[65536];
    const int tid = threadIdx.x;

    if (blockIdx.x < S1_BLOCKS) {
        // ================= scatter1 =================
        unsigned* cbuf  = (unsigned*)smem;                    // CH1 * 4 = 8192
        int* cnt_s  = (int*)(smem + CH1 * 4);
        int* off_s  = cnt_s + NCOARSE;
        int* cur_s  = off_s + NCOARSE;
        int* gpos_s = cur_s + NCOARSE;
        const int base = blockIdx.x * CH1;
        const int n    = min(CH1, NE - base);

        for (int i = tid; i < NCOARSE; i += 256) cnt_s[i] = 0;
        __syncthreads();

        unsigned ent[CH1 / 256];
        #pragma unroll
        for (int j = 0; j < CH1 / 256; ++j) {
            int li = j * 256 + tid;
            if (li < n) {
                int e = base + li;
                unsigned d = (unsigned)dst[e];
                unsigned s = (unsigned)src[e];
                unsigned b = d >> 8;
                ent[j] = (b << 24) | ((d & 255u) << 16) | s;
                atomicAdd(&cnt_s[b], 1);
            }
        }
        __syncthreads();

        if (tid < 64) {
            int i0 = tid * 4;
            int c0 = (i0 + 0 < NCOARSE) ? cnt_s[i0 + 0] : 0;
            int c1 = (i0 + 1 < NCOARSE) ? cnt_s[i0 + 1] : 0;
            int c2 = (i0 + 2 < NCOARSE) ? cnt_s[i0 + 2] : 0;
            int c3 = (i0 + 3 < NCOARSE) ? cnt_s[i0 + 3] : 0;
            int s = c0 + c1 + c2 + c3;
            int x = s;
            #pragma unroll
            for (int o = 1; o < 64; o <<= 1) {
                int y = __shfl_up(x, o, 64);
                if (tid >= o) x += y;
            }
            int ex = x - s;
            if (i0 + 0 < NCOARSE) { off_s[i0 + 0] = ex;                cur_s[i0 + 0] = ex; }
            if (i0 + 1 < NCOARSE) { off_s[i0 + 1] = ex + c0;           cur_s[i0 + 1] = ex + c0; }
            if (i0 + 2 < NCOARSE) { off_s[i0 + 2] = ex + c0 + c1;      cur_s[i0 + 2] = ex + c0 + c1; }
            if (i0 + 3 < NCOARSE) { off_s[i0 + 3] = ex + c0 + c1 + c2; cur_s[i0 + 3] = ex + c0 + c1 + c2; }
        }
        __syncthreads();

        #pragma unroll
        for (int j = 0; j < CH1 / 256; ++j) {
            int li = j * 256 + tid;
            if (li < n) {
                unsigned b = ent[j] >> 24;
                int p = atomicAdd(&cur_s[b], 1);
                cbuf[p] = ent[j];
            }
        }
        __syncthreads();

        if (tid < NCOARSE) {
            int len = cnt_s[tid];
            gpos_s[tid] = (len > 0) ? atomicAdd(&gcur[tid], len) : 0;
        }
        __syncthreads();

        for (int i = tid; i < n; i += 256) {
            unsigned e2 = cbuf[i];
            unsigned b  = e2 >> 24;
            int gp = gpos_s[b] + (i - off_s[b]);
            if (gp < CCAP)
                pairsC[(size_t)b * CCAP + gp] = e2 & 0xFFFFFFu;
        }
    } else {
        // ================= GEMM1 (NCOLS=256, fp32 inputs) =================
        short* Wt = (short*)smem;     // 256*128*2 = 65536
        const int gb = blockIdx.x - S1_BLOCKS;
        {
            const int c = tid;
            const float* wcol = (c < 128) ? (Wa + c) : (Wb + (c - 128));
            for (int kc = 0; kc < 16; ++kc) {
                int k = kc * 8;
                short8 tmp;
                #pragma unroll
                for (int j = 0; j < 8; ++j)
                    tmp[j] = (short)f2bf(wcol[(size_t)(k + j) * 128]);
                int chunk = (kc ^ (c & 7));
                *(short8*)&Wt[c * 128 + chunk * 8] = tmp;
            }
        }
        __syncthreads();

        const int wav = tid >> 6, lane = tid & 63;
        const int rowBase = gb * 64 + wav * 16;
        const int r = lane & 15, g = lane >> 4;
        const int row = rowBase + r;
        const int rowC = (row < NN) ? row : (NN - 1);

        f32x4 acc[16];
        #pragma unroll
        for (int t = 0; t < 16; ++t) acc[t] = (f32x4){0.f, 0.f, 0.f, 0.f};

        #pragma unroll
        for (int ks = 0; ks < 4; ++ks) {
            short8 afrag;
            const float* xrow = (rowC < N_USER)
                ? (user + (size_t)rowC * 128)
                : (item + (size_t)(rowC - N_USER) * 128);
            float4 v0 = *(const float4*)(xrow + ks * 32 + g * 8);
            float4 v1 = *(const float4*)(xrow + ks * 32 + g * 8 + 4);
            afrag[0] = (short)f2bf(v0.x); afrag[1] = (short)f2bf(v0.y);
            afrag[2] = (short)f2bf(v0.z); afrag[3] = (short)f2bf(v0.w);
            afrag[4] = (short)f2bf(v1.x); afrag[5] = (short)f2bf(v1.y);
            afrag[6] = (short)f2bf(v1.z); afrag[7] = (short)f2bf(v1.w);
            const int kc = ks * 4 + g;
            #pragma unroll
            for (int t = 0; t < 16; ++t) {
                int c = t * 16 + r;
                short8 bfrag = *(const short8*)&Wt[c * 128 + (kc ^ (c & 7)) * 8];
                acc[t] = __builtin_amdgcn_mfma_f32_16x16x32_bf16(afrag, bfrag, acc[t], 0, 0, 0);
            }
        }

        // cols 0..127 (X@W1l, mean part) -> fp8 bufA; cols 128..255 -> bf16 bufR
        #pragma unroll
        for (int t = 0; t < 16; ++t) {
            #pragma unroll
            for (int q = 0; q < 4; ++q) {
                int orow = rowBase + g * 4 + q;
                if (orow < NN) {
                    if (t < 8)
                        bufA[(size_t)orow * 128 + t * 16 + r] = f2fp8(acc[t][q]);
                    else
                        bufR[(size_t)orow * 128 + (t - 8) * 16 + r] = f2bf(acc[t][q]);
                }
            }
        }
    }
}

// ---------------------------------------------------------------------------
// Scatter pass 2: split each coarse stream into its 8 fine 32-node buckets.
// ---------------------------------------------------------------------------
__global__ __launch_bounds__(256) void scatter2_kernel(
    const int* __restrict__ gcur, const unsigned* __restrict__ pairsC,
    unsigned* __restrict__ pairsF, int* __restrict__ finCur)
{
    __shared__ unsigned cbuf[CH2];
    __shared__ int cnt8[8], off8[8], cur8[8], gbase8[8];
    const int b   = blockIdx.x >> 2;
    const int c   = blockIdx.x & 3;
    const int tid = threadIdx.x;
    const int total = min(gcur[b], CCAP);
    const int start = c * CH2;
    const int n = min(CH2, total - start);
    if (n <= 0) return;
    if (tid < 8) cnt8[tid] = 0;
    __syncthreads();

    const unsigned* pc = pairsC + (size_t)b * CCAP + start;
    unsigned ent[CH2 / 256];
    #pragma unroll
    for (int j = 0; j < CH2 / 256; ++j) {
        int li = j * 256 + tid;
        if (li < n) {
            unsigned pk = pc[li];
            ent[j] = pk;
            atomicAdd(&cnt8[(pk >> 21) & 7], 1);
        }
    }
    __syncthreads();
    if (tid == 0) {
        int a = 0;
        #pragma unroll
        for (int f = 0; f < 8; ++f) { off8[f] = a; cur8[f] = a; a += cnt8[f]; }
    }
    __syncthreads();
    #pragma unroll
    for (int j = 0; j < CH2 / 256; ++j) {
        int li = j * 256 + tid;
        if (li < n) {
            int f = (ent[j] >> 21) & 7;
            int p = atomicAdd(&cur8[f], 1);
            cbuf[p] = ent[j];
        }
    }
    __syncthreads();
    if (tid < 8) {
        int len = cnt8[tid];
        gbase8[tid] = (len > 0) ? atomicAdd(&finCur[b * 8 + tid], len) : 0;
    }
    __syncthreads();
    for (int i = tid; i < n; i += 256) {
        unsigned e2 = cbuf[i];
        int f = (e2 >> 21) & 7;
        int rel = gbase8[f] + (i - off8[f]);
        if (rel < BCAPF)
            pairsF[(size_t)(b * 8 + f) * BCAPF + rel] = e2 & 0x1FFFFFu;
    }
}

// ---------------------------------------------------------------------------
// GEMM2: mean part outM[NN][64] fp8 = x1b @ W2l ; root outR[NN][64] bf16 = x1b @ W2r
// ---------------------------------------------------------------------------
__global__ __launch_bounds__(256) void mfma_gemm2_kernel(
    const unsigned short* __restrict__ x1b,
    const float* __restrict__ Wa, const float* __restrict__ Wb,
    unsigned char* __restrict__ outM, unsigned short* __restrict__ outR)
{
    __shared__ short Wt[128 * 128];
    const int tid = threadIdx.x;
    {
        const int c  = tid & 127;
        const int k0 = (tid >> 7) * 64;
        const float* wcol = (c < 64) ? (Wa + c) : (Wb + (c - 64));
        for (int kc = 0; kc < 8; ++kc) {
            int k = k0 + kc * 8;
            short8 tmp;
            #pragma unroll
            for (int j = 0; j < 8; ++j)
                tmp[j] = (short)f2bf(wcol[(size_t)(k + j) * 64]);
            int chunk = ((k >> 3) ^ (c & 7));
            *(short8*)&Wt[c * 128 + chunk * 8] = tmp;
        }
    }
    __syncthreads();

    const int wav = tid >> 6, lane = tid & 63;
    const int rowBase = blockIdx.x * 64 + wav * 16;
    const int r = lane & 15, g = lane >> 4;
    const int row = rowBase + r;
    const int rowC = (row < NN) ? row : (NN - 1);

    f32x4 acc[8];
    #pragma unroll
    for (int t = 0; t < 8; ++t) acc[t] = (f32x4){0.f, 0.f, 0.f, 0.f};

    #pragma unroll
    for (int ks = 0; ks < 4; ++ks) {
        const unsigned short* xrow = x1b + (size_t)rowC * 128;
        short8 afrag = *(const short8*)(xrow + ks * 32 + g * 8);
        const int kc = ks * 4 + g;
        #pragma unroll
        for (int t = 0; t < 8; ++t) {
            int c = t * 16 + r;
            short8 bfrag = *(const short8*)&Wt[c * 128 + (kc ^ (c & 7)) * 8];
            acc[t] = __builtin_amdgcn_mfma_f32_16x16x32_bf16(afrag, bfrag, acc[t], 0, 0, 0);
        }
    }

    // tiles 0..3 = x1@W2l (mean part) -> fp8; tiles 4..7 = x1@W2r (root) -> bf16
    #pragma unroll
    for (int t = 0; t < 8; ++t) {
        #pragma unroll
        for (int q = 0; q < 4; ++q) {
            int orow = rowBase + g * 4 + q;
            if (orow < NN) {
                if (t < 4)
                    outM[(size_t)orow * 64 + t * 16 + r] = f2fp8(acc[t][q]);
                else
                    outR[(size_t)orow * 64 + (t - 4) * 16 + r] = f2bf(acc[t][q]);
            }
        }
    }
}

// ---------------------------------------------------------------------------
// Aggregation layer 1: one block per 32-node fine bucket.
// LDS counting sort (pairsF read once), persist sorted list for agg2, then
// fp8 wide gather: 8 lanes/edge x 16 B (=128 B row), 8 edges/wave-inst,
// unroll x2. fp32 accumulate.
//   x1b[g] = bf16( leaky( mean_j(bufA[j]) + b1 + bufR[g] ) )
// ---------------------------------------------------------------------------
__global__ __launch_bounds__(256) void agg1_kernel(
    const unsigned char* __restrict__ bufA, const unsigned short* __restrict__ bufR,
    const int* __restrict__ finCur, const unsigned* __restrict__ pairs,
    const float* __restrict__ b1, unsigned* __restrict__ x1b,
    unsigned* __restrict__ sortedF, int* __restrict__ offF)
{
    __shared__ __align__(4) unsigned short sp[BCAPF];
    __shared__ int cnt_d[32];
    __shared__ int off_d[33];
    __shared__ int cur_d[32];
    const int b = blockIdx.x, tid = threadIdx.x;
    if (tid < 32) cnt_d[tid] = 0;
    __syncthreads();

    const int cnt = min(finCur[b], BCAPF);
    const unsigned* pb = pairs + (size_t)b * BCAPF;
    unsigned entf[5];
    #pragma unroll
    for (int j = 0; j < 5; ++j) {
        int i = j * 256 + tid;
        entf[j] = (i < cnt) ? pb[i] : 0xFFFFFFFFu;
    }
    #pragma unroll
    for (int j = 0; j < 5; ++j)
        if (entf[j] != 0xFFFFFFFFu) atomicAdd(&cnt_d[entf[j] >> 16], 1);
    __syncthreads();
    if (tid == 0) {
        int a = 0;
        #pragma unroll
        for (int k = 0; k < 32; ++k) { off_d[k] = a; cur_d[k] = a; a += cnt_d[k]; }
        off_d[32] = a;
    }
    __syncthreads();
    #pragma unroll
    for (int j = 0; j < 5; ++j) {
        if (entf[j] != 0xFFFFFFFFu) {
            int p = atomicAdd(&cur_d[entf[j] >> 16], 1);
            sp[p] = (unsigned short)(entf[j] & 0xffffu);
        }
    }
    __syncthreads();

    // persist sorted list + offsets for agg2
    for (int i = tid; i * 2 < cnt; i += 256)
        sortedF[(size_t)b * SPW + i] = ((const unsigned*)sp)[i];
    if (tid < 33) offF[b * 33 + tid] = off_d[tid];

    const int wid  = tid >> 6, lane = tid & 63;
    const int egrp = lane >> 3;        // 0..7 edge slot
    const int cchk = lane & 7;         // col chunk (16 fp8 = 16 B)

    for (int r = wid; r < 32; r += 4) {
        int g = b * 32 + r;
        if (g >= NN) continue;
        int beg = off_d[r], end = off_d[r + 1];
        float acc[16] = {};
        int p = beg + egrp;
        for (; p + 8 < end; p += 16) {
            int s0 = sp[p], s1 = sp[p + 8];
            uint4 v0 = *(const uint4*)(bufA + (unsigned)s0 * 128 + cchk * 16);
            uint4 v1 = *(const uint4*)(bufA + (unsigned)s1 * 128 + cchk * 16);
            float f0[4], f1[4], f2[4], f3[4];
            fp8x4(v0.x, f0); fp8x4(v0.y, f1); fp8x4(v0.z, f2); fp8x4(v0.w, f3);
            #pragma unroll
            for (int j = 0; j < 4; ++j) {
                acc[j]      += f0[j]; acc[4 + j]  += f1[j];
                acc[8 + j]  += f2[j]; acc[12 + j] += f3[j];
            }
            fp8x4(v1.x, f0); fp8x4(v1.y, f1); fp8x4(v1.z, f2); fp8x4(v1.w, f3);
            #pragma unroll
            for (int j = 0; j < 4; ++j) {
                acc[j]      += f0[j]; acc[4 + j]  += f1[j];
                acc[8 + j]  += f2[j]; acc[12 + j] += f3[j];
            }
        }
        if (p < end) {
            int s0 = sp[p];
            uint4 v0 = *(const uint4*)(bufA + (unsigned)s0 * 128 + cchk * 16);
            float f0[4], f1[4], f2[4], f3[4];
            fp8x4(v0.x, f0); fp8x4(v0.y, f1); fp8x4(v0.z, f2); fp8x4(v0.w, f3);
            #pragma unroll
            for (int j = 0; j < 4; ++j) {
                acc[j]      += f0[j]; acc[4 + j]  += f1[j];
                acc[8 + j]  += f2[j]; acc[12 + j] += f3[j];
            }
        }
        // combine the 8 edge groups
        #pragma unroll
        for (int j = 0; j < 16; ++j) {
            acc[j] += __shfl_xor(acc[j], 32);
            acc[j] += __shfl_xor(acc[j], 16);
            acc[j] += __shfl_xor(acc[j], 8);
        }
        if (egrp == 0) {
            float inv = 1.0f / fmaxf((float)(end - beg), 1.0f);
            const unsigned short* rr = bufR + (size_t)g * 128 + cchk * 16;
            ushort8x rv0 = *(const ushort8x*)rr;
            ushort8x rv1 = *(const ushort8x*)(rr + 8);
            const float* bp = b1 + cchk * 16;
            unsigned w[8];
            #pragma unroll
            for (int jj = 0; jj < 8; ++jj) {
                int j0 = 2 * jj, j1 = 2 * jj + 1;
                float r0 = (jj < 4) ? bfu(rv0[j0 & 7]) : bfu(rv1[j0 & 7]);
                float r1 = (jj < 4) ? bfu(rv0[j1 & 7]) : bfu(rv1[j1 & 7]);
                float o0 = acc[j0] * inv + bp[j0] + r0;
                float o1 = acc[j1] * inv + bp[j1] + r1;
                o0 = (o0 > 0.f) ? o0 : 0.01f * o0;
                o1 = (o1 > 0.f) ? o1 : 0.01f * o1;
                w[jj] = (unsigned)f2bf(o0) | ((unsigned)f2bf(o1) << 16);
            }
            unsigned* xo = x1b + (size_t)g * 64 + cchk * 8;
            *(uint4*)xo       = make_uint4(w[0], w[1], w[2], w[3]);
            *(uint4*)(xo + 4) = make_uint4(w[4], w[5], w[6], w[7]);
        }
    }
}

// ---------------------------------------------------------------------------
// Aggregation layer 2: reuses agg1's sorted lists. fp8 gather from L2-resident
// bufM2 [NN][64] (3.9 MB): 8 lanes/edge x 8 B, 8 edges/wave-inst, unroll x2.
//   out[g] = mean_j(bufM2[j]) + b2 + bufR2[g]
// ---------------------------------------------------------------------------
__global__ __launch_bounds__(256) void agg2_kernel(
    const unsigned char* __restrict__ bufM2, const unsigned short* __restrict__ bufR2,
    const unsigned* __restrict__ sortedF, const int* __restrict__ offF,
    const float* __restrict__ b2, float* __restrict__ out)
{
    __shared__ __align__(4) unsigned short sp[BCAPF];
    __shared__ int off_d[33];
    const int b = blockIdx.x, tid = threadIdx.x;
    if (tid < 33) off_d[tid] = offF[b * 33 + tid];
    __syncthreads();
    const int cnt = off_d[32];
    const unsigned* spg = sortedF + (size_t)b * SPW;
    for (int i = tid; i * 2 < cnt; i += 256)
        ((unsigned*)sp)[i] = spg[i];
    __syncthreads();

    const int wid  = tid >> 6, lane = tid & 63;
    const int egrp = lane >> 3;        // 0..7 edge slot
    const int cchk = lane & 7;         // col chunk (8 fp8 = 8 B)

    for (int r = wid; r < 32; r += 4) {
        int g = b * 32 + r;
        if (g >= NN) continue;
        int beg = off_d[r], end = off_d[r + 1];
        float acc[8] = {};
        int p = beg + egrp;
        for (; p + 8 < end; p += 16) {
            int s0 = sp[p], s1 = sp[p + 8];
            uint2 v0 = *(const uint2*)(bufM2 + (unsigned)s0 * 64 + cchk * 8);
            uint2 v1 = *(const uint2*)(bufM2 + (unsigned)s1 * 64 + cchk * 8);
            float f0[4], f1[4];
            fp8x4(v0.x, f0); fp8x4(v0.y, f1);
            #pragma unroll
            for (int j = 0; j < 4; ++j) { acc[j] += f0[j]; acc[4 + j] += f1[j]; }
            fp8x4(v1.x, f0); fp8x4(v1.y, f1);
            #pragma unroll
            for (int j = 0; j < 4; ++j) { acc[j] += f0[j]; acc[4 + j] += f1[j]; }
        }
        if (p < end) {
            int s0 = sp[p];
            uint2 v0 = *(const uint2*)(bufM2 + (unsigned)s0 * 64 + cchk * 8);
            float f0[4], f1[4];
            fp8x4(v0.x, f0); fp8x4(v0.y, f1);
            #pragma unroll
            for (int j = 0; j < 4; ++j) { acc[j] += f0[j]; acc[4 + j] += f1[j]; }
        }
        #pragma unroll
        for (int j = 0; j < 8; ++j) {
            acc[j] += __shfl_xor(acc[j], 32);
            acc[j] += __shfl_xor(acc[j], 16);
            acc[j] += __shfl_xor(acc[j], 8);
        }
        if (egrp == 0) {
            float inv = 1.0f / fmaxf((float)(end - beg), 1.0f);
            ushort8x rv = *(const ushort8x*)(bufR2 + (size_t)g * 64 + cchk * 8);
            float4 bb0 = *(const float4*)(b2 + cchk * 8);
            float4 bb1 = *(const float4*)(b2 + cchk * 8 + 4);
            float bbf[8] = {bb0.x, bb0.y, bb0.z, bb0.w, bb1.x, bb1.y, bb1.z, bb1.w};
            float4 o0, o1;
            o0.x = acc[0] * inv + bbf[0] + bfu(rv[0]);
            o0.y = acc[1] * inv + bbf[1] + bfu(rv[1]);
            o0.z = acc[2] * inv + bbf[2] + bfu(rv[2]);
            o0.w = acc[3] * inv + bbf[3] + bfu(rv[3]);
            o1.x = acc[4] * inv + bbf[4] + bfu(rv[4]);
            o1.y = acc[5] * inv + bbf[5] + bfu(rv[5]);
            o1.z = acc[6] * inv + bbf[6] + bfu(rv[6]);
            o1.w = acc[7] * inv + bbf[7] + bfu(rv[7]);
            *(float4*)&out[(size_t)g * 64 + cchk * 8]     = o0;
            *(float4*)&out[(size_t)g * 64 + cchk * 8 + 4] = o1;
        }
    }
}

// ---------------------------------------------------------------------------
extern "C" void kernel_launch(void* const* d_in, const int* in_sizes, int n_in,
                              void* d_out, int out_size, void* d_ws, size_t ws_size,
                              hipStream_t stream) {
    const float* user = (const float*)d_in[0];
    const float* item = (const float*)d_in[1];
    const float* W1l  = (const float*)d_in[2];
    const float* b1   = (const float*)d_in[3];
    const float* W1r  = (const float*)d_in[4];
    const float* W2l  = (const float*)d_in[5];
    const float* b2   = (const float*)d_in[6];
    const float* W2r  = (const float*)d_in[7];
    const int*   edge = (const int*)d_in[8];
    const int* srcIdx = edge;          // edge_index[0]
    const int* dstIdx = edge + NE;     // edge_index[1]
    float* out = (float*)d_out;

    char* ws = (char*)d_ws;
    size_t off = 0;
    auto alloc = [&](size_t bytes) {
        void* p = ws + off;
        off += (bytes + 255) & ~(size_t)255;
        return p;
    };
    int*      gcur    = (int*)alloc((size_t)NCOARSE * 4);
    int*      finCur  = (int*)alloc((size_t)NFINE * 4);
    unsigned* pairsC  = (unsigned*)alloc((size_t)NCOARSE * CCAP * 4);     // 6.9 MB
    unsigned* pairsF  = (unsigned*)alloc((size_t)NFINE * BCAPF * 4);      // 9.9 MB
    unsigned* sortedF = (unsigned*)alloc((size_t)NFINE * SPW * 4);        // 4.9 MB
    int*      offF    = (int*)alloc((size_t)NFINE * 33 * 4);              // 254 KB
    unsigned char*  bufA = (unsigned char*) alloc((size_t)NN * 128);      // fp8 L1 mean, 7.9 MB
    unsigned short* bufR = (unsigned short*)alloc((size_t)NN * 128 * 2);  // bf16 L1 root, 15.7 MB
    unsigned* x1b    = (unsigned*)alloc((size_t)NN * 128 * 2);            // layer-1 act bf16
    // layer-2 staging aliases (dead-after-agg1 buffers):
    unsigned char*  bufM2 = bufA;                      // fp8 [NN][64] = 3.9 MB <= 7.9
    unsigned short* bufR2 = bufR;                      // bf16 [NN][64] = 7.9 MB <= 15.7

    (void)hipMemsetAsync(gcur, 0, (size_t)NCOARSE * 4, stream);
    (void)hipMemsetAsync(finCur, 0, (size_t)NFINE * 4, stream);

    // scatter1 + GEMM1 fused (independent)
    fused1_kernel<<<S1_BLOCKS + 961, 256, 0, stream>>>(
        srcIdx, dstIdx, gcur, pairsC, user, item, W1l, W1r, bufA, bufR);

    scatter2_kernel<<<NCOARSE * S2_SPLIT, 256, 0, stream>>>(gcur, pairsC, pairsF, finCur);

    agg1_kernel<<<NFINE, 256, 0, stream>>>(bufA, bufR, finCur, pairsF, b1, x1b, sortedF, offF);

    mfma_gemm2_kernel<<<961, 256, 0, stream>>>((const unsigned short*)x1b, W2l, W2r, bufM2, bufR2);

    agg2_kernel<<<NFINE, 256, 0, stream>>>(bufM2, bufR2, sortedF, offF, b2, out);
}